// Round 1
// baseline (100.116 us; speedup 1.0000x reference)
//
#include <hip/hip_runtime.h>
#include <math.h>

// Problem constants (CapsShapeLayer): B=256, D=10, M=32, P=36, I=8, O=16, 3 iters
#define BB 256
#define DD 10
#define MM 32
#define PP 36
#define II 8
#define OO 16

__device__ __forceinline__ float dot8(float4 a0, float4 a1, float4 b0, float4 b1) {
    return a0.x*b0.x + a0.y*b0.y + a0.z*b0.z + a0.w*b0.w
         + a1.x*b1.x + a1.y*b1.y + a1.z*b1.z + a1.w*b1.w;
}

// One block per batch element. Never materializes u_hat:
//   s[d,o]   = sum_{m,i} W[d,m,o,i] * y[d,m,i],  y[d,m,i] = sum_p c[d,m,p] x[m,p,i]
//   b[d,m,p]+= sum_i x[m,p,i] * z[d,m,i],        z[d,m,i] = sum_o W[d,m,o,i] v[d,o]
__global__ void __launch_bounds__(256) caps_routing(
    const float* __restrict__ x,   // (B, M, P, I)
    const float* __restrict__ W,   // (1, D, M, 1, O, I) -> (D, M, O, I)
    float* __restrict__ out)       // (B, D, O)
{
    const int bidx = blockIdx.x;
    const int tid  = threadIdx.x;
    const float* __restrict__ xb = x + (size_t)bidx * (MM * PP * II);

    __shared__ __align__(16) float b_l [DD*MM*PP];  // 46080 B routing logits
    __shared__ __align__(16) float lse [MM*PP];     //  4608 B logsumexp over d
    __shared__ __align__(16) float yz  [DD*MM*II];  // 10240 B y / z scratch
    __shared__ __align__(16) float ybar[MM*II];     //  1024 B iter-1 y (d-independent)
    __shared__ __align__(16) float s_l [DD*OO];     //   640 B
    __shared__ __align__(16) float v_l [DD*OO];     //   640 B
    // total ~61.8 KB (<= 64 KB per workgroup on purpose)

    // ================= iteration 1: b == 0 -> c = 1/D exactly =================
    {
        const int m = tid >> 3, i = tid & 7;   // 32*8 = 256 threads, one (m,i) each
        float acc = 0.f;
        for (int p = 0; p < PP; ++p) acc += xb[(m*PP + p)*II + i];
        ybar[tid] = 0.1f * acc;                // 1/D = 0.1
    }
    __syncthreads();

    // s[d,o] = sum_{m,i} W * ybar
    if (tid < DD*OO) {
        const int d = tid >> 4, o = tid & 15;
        float acc = 0.f;
        for (int m = 0; m < MM; ++m) {
            const float4* wp = (const float4*)(W + (size_t)((d*MM + m)*OO + o) * II);
            const float4* yp = (const float4*)(ybar + m*II);
            acc += dot8(wp[0], wp[1], yp[0], yp[1]);
        }
        s_l[tid] = acc;
    }
    __syncthreads();

    // v = squash(s): sq over o; v = (sq/(1+sq)) * s / sqrt(sq+eps)
    if (tid < DD*OO) {
        const int d = tid >> 4;
        float sq = 0.f;
        #pragma unroll
        for (int o2 = 0; o2 < OO; ++o2) { const float t = s_l[d*OO + o2]; sq += t*t; }
        const float nrm   = sqrtf(sq + 1e-7f);
        const float scale = sq / (1.f + sq);
        v_l[tid] = scale * (s_l[tid] / nrm);
    }
    __syncthreads();

    // z[d,m,i] = sum_o W[d,m,o,i] * v[d,o]   (into yz)
    for (int slot = tid; slot < DD*MM*II; slot += 256) {
        const int d  = slot >> 8;          // MM*II == 256
        const int mi = slot & 255;
        const int m  = mi >> 3, i = mi & 7;
        const float* wp = W + (size_t)((d*MM + m)*OO) * II + i;
        const float* vp = v_l + d*OO;
        float acc = 0.f;
        #pragma unroll
        for (int o = 0; o < OO; ++o) acc += wp[o*II] * vp[o];
        yz[slot] = acc;
    }
    __syncthreads();

    // b[d,m,p] = sum_i x[m,p,i] * z[d,m,i]   (b0 == 0)
    for (int slot = tid; slot < DD*MM*PP; slot += 256) {
        const int d  = slot / (MM*PP);
        const int mp = slot - d*(MM*PP);
        const int m  = mp / PP;
        const int p  = mp - m*PP;
        const float4* xp = (const float4*)(xb + (size_t)(m*PP + p)*II);
        const float4* zp = (const float4*)(yz + (size_t)(d*MM + m)*II);
        b_l[slot] = dot8(xp[0], xp[1], zp[0], zp[1]);
    }
    __syncthreads();

    // ================= iteration 2: softmax over d =================
    for (int mp = tid; mp < MM*PP; mp += 256) {
        float mx = b_l[mp];
        #pragma unroll
        for (int d = 1; d < DD; ++d) mx = fmaxf(mx, b_l[d*(MM*PP) + mp]);
        float sum = 0.f;
        #pragma unroll
        for (int d = 0; d < DD; ++d) sum += __expf(b_l[d*(MM*PP) + mp] - mx);
        lse[mp] = mx + __logf(sum);
    }
    __syncthreads();

    // y[d,m,i] = sum_p exp(b - lse) * x[m,p,i]
    for (int slot = tid; slot < DD*MM; slot += 256) {
        const int d = slot >> 5, m = slot & 31;
        const float* bp = b_l + (size_t)(d*MM + m)*PP;
        const float* lp = lse + m*PP;
        float a0=0.f,a1=0.f,a2=0.f,a3=0.f,a4=0.f,a5=0.f,a6=0.f,a7=0.f;
        for (int p = 0; p < PP; ++p) {
            const float c = __expf(bp[p] - lp[p]);
            const float4* xp = (const float4*)(xb + (size_t)(m*PP + p)*II);
            const float4 u0 = xp[0], u1 = xp[1];
            a0 += c*u0.x; a1 += c*u0.y; a2 += c*u0.z; a3 += c*u0.w;
            a4 += c*u1.x; a5 += c*u1.y; a6 += c*u1.z; a7 += c*u1.w;
        }
        float* yp = yz + (size_t)slot * II;
        yp[0]=a0; yp[1]=a1; yp[2]=a2; yp[3]=a3;
        yp[4]=a4; yp[5]=a5; yp[6]=a6; yp[7]=a7;
    }
    __syncthreads();

    // s[d,o] = sum_{m,i} W * y
    if (tid < DD*OO) {
        const int d = tid >> 4, o = tid & 15;
        float acc = 0.f;
        for (int m = 0; m < MM; ++m) {
            const float4* wp = (const float4*)(W + (size_t)((d*MM + m)*OO + o) * II);
            const float4* yp = (const float4*)(yz + (size_t)(d*MM + m)*II);
            acc += dot8(wp[0], wp[1], yp[0], yp[1]);
        }
        s_l[tid] = acc;
    }
    __syncthreads();

    if (tid < DD*OO) {
        const int d = tid >> 4;
        float sq = 0.f;
        #pragma unroll
        for (int o2 = 0; o2 < OO; ++o2) { const float t = s_l[d*OO + o2]; sq += t*t; }
        const float nrm   = sqrtf(sq + 1e-7f);
        const float scale = sq / (1.f + sq);
        v_l[tid] = scale * (s_l[tid] / nrm);
    }
    __syncthreads();

    // z = W . v (overwrite yz; safe, y consumed above + barrier)
    for (int slot = tid; slot < DD*MM*II; slot += 256) {
        const int d  = slot >> 8;
        const int mi = slot & 255;
        const int m  = mi >> 3, i = mi & 7;
        const float* wp = W + (size_t)((d*MM + m)*OO) * II + i;
        const float* vp = v_l + d*OO;
        float acc = 0.f;
        #pragma unroll
        for (int o = 0; o < OO; ++o) acc += wp[o*II] * vp[o];
        yz[slot] = acc;
    }
    __syncthreads();

    // b += x . z
    for (int slot = tid; slot < DD*MM*PP; slot += 256) {
        const int d  = slot / (MM*PP);
        const int mp = slot - d*(MM*PP);
        const int m  = mp / PP;
        const int p  = mp - m*PP;
        const float4* xp = (const float4*)(xb + (size_t)(m*PP + p)*II);
        const float4* zp = (const float4*)(yz + (size_t)(d*MM + m)*II);
        b_l[slot] += dot8(xp[0], xp[1], zp[0], zp[1]);
    }
    __syncthreads();

    // ================= final: softmax over P (axis=3!) =================
    for (int slot = tid; slot < DD*MM; slot += 256) {
        const int d = slot >> 5, m = slot & 31;
        const float* bp = b_l + (size_t)(d*MM + m)*PP;
        float mx = bp[0];
        for (int p = 1; p < PP; ++p) mx = fmaxf(mx, bp[p]);
        float sum = 0.f;
        for (int p = 0; p < PP; ++p) sum += __expf(bp[p] - mx);
        const float rs = 1.f / sum;
        float a0=0.f,a1=0.f,a2=0.f,a3=0.f,a4=0.f,a5=0.f,a6=0.f,a7=0.f;
        for (int p = 0; p < PP; ++p) {
            const float c = __expf(bp[p] - mx) * rs;
            const float4* xp = (const float4*)(xb + (size_t)(m*PP + p)*II);
            const float4 u0 = xp[0], u1 = xp[1];
            a0 += c*u0.x; a1 += c*u0.y; a2 += c*u0.z; a3 += c*u0.w;
            a4 += c*u1.x; a5 += c*u1.y; a6 += c*u1.z; a7 += c*u1.w;
        }
        float* yp = yz + (size_t)slot * II;
        yp[0]=a0; yp[1]=a1; yp[2]=a2; yp[3]=a3;
        yp[4]=a4; yp[5]=a5; yp[6]=a6; yp[7]=a7;
    }
    __syncthreads();

    // s[d,o] = sum_{m,i} W * y3
    if (tid < DD*OO) {
        const int d = tid >> 4, o = tid & 15;
        float acc = 0.f;
        for (int m = 0; m < MM; ++m) {
            const float4* wp = (const float4*)(W + (size_t)((d*MM + m)*OO + o) * II);
            const float4* yp = (const float4*)(yz + (size_t)(d*MM + m)*II);
            acc += dot8(wp[0], wp[1], yp[0], yp[1]);
        }
        s_l[tid] = acc;
    }
    __syncthreads();

    // out = squash(s)
    if (tid < DD*OO) {
        const int d = tid >> 4;
        float sq = 0.f;
        #pragma unroll
        for (int o2 = 0; o2 < OO; ++o2) { const float t = s_l[d*OO + o2]; sq += t*t; }
        const float nrm   = sqrtf(sq + 1e-7f);
        const float scale = sq / (1.f + sq);
        out[(size_t)bidx * (DD*OO) + tid] = scale * (s_l[tid] / nrm);
    }
}

extern "C" void kernel_launch(void* const* d_in, const int* in_sizes, int n_in,
                              void* d_out, int out_size, void* d_ws, size_t ws_size,
                              hipStream_t stream) {
    (void)in_sizes; (void)n_in; (void)out_size; (void)d_ws; (void)ws_size;
    const float* x = (const float*)d_in[0];  // (B, M, P, I)
    const float* W = (const float*)d_in[1];  // (1, D, M, 1, O, I)
    float* out = (float*)d_out;              // (B, D, O)
    caps_routing<<<dim3(BB), dim3(256), 0, stream>>>(x, W, out);
}